// Round 1
// 628.202 us; speedup vs baseline: 1.1816x; 1.1816x over previous
//
#include <hip/hip_runtime.h>
#include <hip/hip_bf16.h>
#include <math.h>

#define HID     2560
#define D_INNER 8192
#define NG      32
#define D_SSM   4096
#define KCONV   4
#define HD      128
#define DS      64
#define LSEQ    1024
#define LC      64
#define NC      (LSEQ / LC)
#define NZ      4224          // z(4096) + dt(32) + D(32) + pad(64)
#define NBIG    12416         // qkv(8192) + NZ
#define EPS_RMS 1e-6f

// ---- gemm_big256 deep-pipeline params ----
#define BKT       32          // K per tile (one 16x16x32 MFMA k-depth)
#define NKT       240         // K' = 3*2560 -> 240 tiles of 32
#define GB_NT     49          // ceil(12416/256) n-tiles (last one clamped)
#define GB_BLOCKS 196         // 49 * 4 m-tiles

typedef short bf16x8 __attribute__((ext_vector_type(8)));
typedef float f32x4 __attribute__((ext_vector_type(4)));

__device__ __forceinline__ float siluf(float x) { return x / (1.f + expf(-x)); }

__device__ __forceinline__ unsigned short f2bf(float x) {
    __hip_bfloat16 b = __float2bfloat16(x);
    return *reinterpret_cast<unsigned short*>(&b);
}
__device__ __forceinline__ float bf2f(unsigned short u) {
    union { unsigned int i; float f; } v;
    v.i = ((unsigned int)u) << 16;
    return v.f;
}

__device__ __forceinline__ void async16(const ushort* g, ushort* l) {
    __builtin_amdgcn_global_load_lds(
        (const __attribute__((address_space(1))) unsigned int*)g,
        (__attribute__((address_space(3))) unsigned int*)l, 16, 0, 0);
}

// counted-vmcnt gate: wave drains its own ds_reads (lgkmcnt 0) but leaves VM
// staging loads in flight across the raw barrier (T4). memory clobber pins
// all global_load_lds / ds_read motion across the gate.
template<int VM>
__device__ __forceinline__ void gate_barrier() {
    asm volatile("s_waitcnt vmcnt(%0) lgkmcnt(0)" :: "n"(VM) : "memory");
    __builtin_amdgcn_s_barrier();
    asm volatile("" ::: "memory");
}

// ---------------- f32 -> (hi, lo) bf16 planes ----------------
__global__ __launch_bounds__(256)
void split_cvt(const float4* __restrict__ in, ushort4* __restrict__ hi,
               ushort4* __restrict__ lo, int n4) {
    int i = blockIdx.x * 256 + threadIdx.x;
    if (i >= n4) return;
    float4 v = in[i];
    ushort4 h, l;
    h.x = f2bf(v.x); l.x = f2bf(v.x - bf2f(h.x));
    h.y = f2bf(v.y); l.y = f2bf(v.y - bf2f(h.y));
    h.z = f2bf(v.z); l.z = f2bf(v.z - bf2f(h.z));
    h.w = f2bf(v.w); l.w = f2bf(v.w - bf2f(h.w));
    hi[i] = h; lo[i] = l;
}

// ---------------- shared MFMA mainloop (kept for gemm_out_splitk) ----------
__device__ __forceinline__ void mfma_core(
    const ushort* __restrict__ Ah, const ushort* __restrict__ Al,
    const ushort* __restrict__ Bh, const ushort* __restrict__ Bl,
    int lda, int ldb, int m0, int n0, int kBeg, int kEnd,
    ushort (&sA)[2][128][32], ushort (&sB)[2][128][32],
    f32x4 (&acc)[4][4], int tid)
{
    const int wave = tid >> 6, lane = tid & 63;
    const int wm = (wave >> 1) * 64, wn = (wave & 1) * 64;
    const int srow = lane >> 2;
    const int scol = (lane & 3) * 8;
    const int r0 = wave * 32;

    for (int k0 = kBeg; k0 < kEnd; k0 += 32) {
        #pragma unroll
        for (int i = 0; i < 2; i++) {
            int rt = r0 + i * 16;
            int rg = rt + srow;
            size_t goffA = (size_t)(m0 + rg) * lda + k0 + scol;
            size_t goffB = (size_t)(n0 + rg) * ldb + k0 + scol;
            async16(Ah + goffA, &sA[0][rt][0]);
            async16(Al + goffA, &sA[1][rt][0]);
            async16(Bh + goffB, &sB[0][rt][0]);
            async16(Bl + goffB, &sB[1][rt][0]);
        }
        __syncthreads();

        const int fr = lane & 15, fk = (lane >> 4) * 8;
        bf16x8 a[2][4], b[2][4];
        #pragma unroll
        for (int t = 0; t < 4; t++) {
            a[0][t] = *(const bf16x8*)&sA[0][wm + t * 16 + fr][fk];
            a[1][t] = *(const bf16x8*)&sA[1][wm + t * 16 + fr][fk];
            b[0][t] = *(const bf16x8*)&sB[0][wn + t * 16 + fr][fk];
            b[1][t] = *(const bf16x8*)&sB[1][wn + t * 16 + fr][fk];
        }
        #pragma unroll
        for (int mt = 0; mt < 4; mt++)
            #pragma unroll
            for (int nt = 0; nt < 4; nt++) {
                acc[mt][nt] = __builtin_amdgcn_mfma_f32_16x16x32_bf16(
                    a[0][mt], b[0][nt], acc[mt][nt], 0, 0, 0);
                acc[mt][nt] = __builtin_amdgcn_mfma_f32_16x16x32_bf16(
                    a[0][mt], b[1][nt], acc[mt][nt], 0, 0, 0);
                acc[mt][nt] = __builtin_amdgcn_mfma_f32_16x16x32_bf16(
                    a[1][mt], b[0][nt], acc[mt][nt], 0, 0, 0);
            }
        __syncthreads();
    }
}

// ---------------- big GEMM, 256x256 tile, 4-slot ring, counted vmcnt --------
// Computes [1024, 12416(+pad)] = hs @ [Wqkv|Wz|Wb|Wa]^T with f32-split bf16
// folded into ONE bf16 GEMM of K'=7680: A-planes [Ah,Ah,Al], B-planes
// [Bh,Bl,Bh] selected per K-third (no materialization).
// cols 0..8191 -> xBC (ldc 8192), cols 8192..12415 -> zq (ldc NZ), rest dropped.
__global__ __launch_bounds__(512, 2)
void gemm_big256(const ushort* __restrict__ Ah, const ushort* __restrict__ Al,
                 const ushort* __restrict__ Bh, const ushort* __restrict__ Bl,
                 float* __restrict__ xBC, float* __restrict__ zq)
{
    // 4 slots x {A,B} x 256 rows x 32 k-elems (bf16) = 128 KiB
    __shared__ ushort lds[4][2][256][32];

    const int tid  = threadIdx.x;
    const int lane = tid & 63, wv = tid >> 6;

    // bijective XCD swizzle (m204) then panel-major decompose:
    // consecutive swizzled ids = 4 M-tiles of one N-panel -> per-XCD L2 reuse.
    int id = blockIdx.x;
    const int qx = GB_BLOCKS / 8, rx = GB_BLOCKS % 8;       // 24, 4
    int xcd = id & 7, lid = id >> 3;
    int sw  = (xcd < rx) ? (xcd * (qx + 1) + lid)
                         : (rx * (qx + 1) + (xcd - rx) * qx + lid);
    const int m0 = (sw & 3) << 8;       // 0..768
    const int n0 = (sw >> 2) << 8;      // 0..12288

    // ---- stage-side lane mapping (rule #21: linear LDS dest, pre-swizzled
    // global source; swizzle: phys_chunk = log_chunk ^ ((row>>1)&3)) ----
    const int rb  = (wv << 4) + (lane >> 2);                    // row in 128-half
    const int csw = (((lane & 3) ^ ((lane >> 3) & 3)) << 3);    // source k-chunk

    auto stage = [&](int kt, int slot) {
        int third = kt / 80;                    // 80 tiles per K-third
        int kk = (kt - third * 80) * BKT;
        const ushort* Ap = (third == 2) ? Al : Ah;   // [Ah, Ah, Al]
        const ushort* Bp = (third == 1) ? Bl : Bh;   // [Bh, Bl, Bh]
        int cs = kk + csw;
        int ar0 = m0 + rb, ar1 = m0 + 128 + rb;
        int br0 = n0 + rb;        if (br0 > NBIG - 1) br0 = NBIG - 1;  // pad clamp
        int br1 = n0 + 128 + rb;  if (br1 > NBIG - 1) br1 = NBIG - 1;
        ushort* dA = &lds[slot][0][wv << 4][0];      // wave-uniform base
        ushort* dB = &lds[slot][1][wv << 4][0];
        async16(Ap + (size_t)ar0 * HID + cs, dA);
        async16(Ap + (size_t)ar1 * HID + cs, dA + 128 * 32);
        async16(Bp + (size_t)br0 * HID + cs, dB);
        async16(Bp + (size_t)br1 * HID + cs, dB + 128 * 32);
    };

    // ---- compute-side: 8 waves as 2M x 4N, per-wave 128x64 ----
    const int wm  = (wv >> 2) << 7;                 // 0 / 128
    const int wn  = (wv & 3) << 6;                  // 0 / 64 / 128 / 192
    const int fr  = lane & 15;
    const int ckr = ((((lane >> 4) ^ ((lane >> 1) & 3))) << 3);  // swizzled read chunk

    f32x4 acc[8][4];
    #pragma unroll
    for (int i = 0; i < 8; i++)
        #pragma unroll
        for (int j = 0; j < 4; j++) acc[i][j] = (f32x4){0.f, 0.f, 0.f, 0.f};

    auto compute = [&](int slot) {
        const ushort* sA = &lds[slot][0][0][0];
        const ushort* sB = &lds[slot][1][0][0];
        bf16x8 a[8], b[4];
        #pragma unroll
        for (int mt = 0; mt < 8; mt++)
            a[mt] = *(const bf16x8*)&sA[(wm + mt * 16 + fr) * 32 + ckr];
        #pragma unroll
        for (int nt = 0; nt < 4; nt++)
            b[nt] = *(const bf16x8*)&sB[(wn + nt * 16 + fr) * 32 + ckr];
        __builtin_amdgcn_s_setprio(1);
        #pragma unroll
        for (int mt = 0; mt < 8; mt++)
            #pragma unroll
            for (int nt = 0; nt < 4; nt++)
                acc[mt][nt] = __builtin_amdgcn_mfma_f32_16x16x32_bf16(
                    a[mt], b[nt], acc[mt][nt], 0, 0, 0);
        __builtin_amdgcn_s_setprio(0);
    };

    // prologue: fill prefetch depth 3 (12 loads/wave in flight)
    stage(0, 0); stage(1, 1); stage(2, 2);

    // steady state: gate vmcnt(8) = tiles kt+1,kt+2 (4 insts each) stay in
    // flight; stage(kt+3) writes slot (kt-1)&3, safe because every wave
    // passed lgkmcnt(0) for its tile-(kt-1) reads before this barrier.
    #pragma unroll 4
    for (int kt = 0; kt < NKT - 4; kt++) {          // 0..235, 236 = 4*59
        gate_barrier<8>();
        stage(kt + 3, (kt + 3) & 3);
        compute(kt & 3);
    }
    gate_barrier<8>(); stage(239, 3); compute(0);   // kt = 236
    gate_barrier<8>(); compute(1);                  // kt = 237
    gate_barrier<4>(); compute(2);                  // kt = 238
    gate_barrier<0>(); compute(3);                  // kt = 239

    // ---- epilogue: C[row][col], col split xBC/zq, pad cols dropped ----
    const int rq = (lane >> 4) << 2;
    #pragma unroll
    for (int mt = 0; mt < 8; mt++) {
        int row = m0 + wm + mt * 16 + rq;
        #pragma unroll
        for (int nt = 0; nt < 4; nt++) {
            int col = n0 + wn + nt * 16 + fr;
            if (col < 8192) {
                #pragma unroll
                for (int r = 0; r < 4; r++)
                    xBC[(size_t)(row + r) * 8192 + col] = acc[mt][nt][r];
            } else if (col < NBIG) {
                #pragma unroll
                for (int r = 0; r < 4; r++)
                    zq[(size_t)(row + r) * NZ + (col - 8192)] = acc[mt][nt][r];
            }
        }
    }
}

// ---------------- out GEMM, split-K x4, atomic accumulate ----------------
__global__ __launch_bounds__(256)
void gemm_out_splitk(const ushort* __restrict__ Ah, const ushort* __restrict__ Al,
                     const ushort* __restrict__ Bh, const ushort* __restrict__ Bl,
                     float* __restrict__ C) {
    __shared__ ushort sA[2][128][32];
    __shared__ ushort sB[2][128][32];
    const int tid = threadIdx.x;
    const int m0 = blockIdx.y * 128, n0 = blockIdx.x * 128;
    const int kBeg = blockIdx.z * (D_SSM / 4), kEnd = kBeg + D_SSM / 4;

    f32x4 acc[4][4];
    #pragma unroll
    for (int i = 0; i < 4; i++)
        #pragma unroll
        for (int j = 0; j < 4; j++) acc[i][j] = (f32x4){0.f, 0.f, 0.f, 0.f};

    mfma_core(Ah, Al, Bh, Bl, D_SSM, D_SSM, m0, n0, kBeg, kEnd, sA, sB, acc, tid);

    const int wave = tid >> 6, lane = tid & 63;
    const int wm = (wave >> 1) * 64, wn = (wave & 1) * 64;
    const int fr = lane & 15, rq = (lane >> 4) * 4;
    #pragma unroll
    for (int mt = 0; mt < 4; mt++)
        #pragma unroll
        for (int nt = 0; nt < 4; nt++) {
            int col = n0 + wn + nt * 16 + fr;
            int row = m0 + wm + mt * 16 + rq;
            #pragma unroll
            for (int r = 0; r < 4; r++)
                atomicAdd(&C[(size_t)(row + r) * HID + col], acc[mt][nt][r]);
        }
}

// ---------------- conv (K=4 causal) + SiLU ----------------
__global__ __launch_bounds__(256)
void conv_silu(const float* __restrict__ xBC, const float* __restrict__ conv_w,
               float* __restrict__ out) {
    int idx = blockIdx.x * 256 + threadIdx.x;
    if (idx >= LSEQ * D_INNER) return;
    int t = idx / D_INNER, c = idx - t * D_INNER;
    float acc = 0.f;
    #pragma unroll
    for (int k = 0; k < KCONV; k++) {
        int tt = t - (KCONV - 1) + k;
        if (tt >= 0) acc += xBC[(size_t)tt * D_INNER + c] * conv_w[c * KCONV + k];
    }
    out[idx] = siluf(acc);
}

// ---------------- S1: softplus(dt)+cumsum ----------------
__global__ __launch_bounds__(1024)
void dt_scan(const float* __restrict__ zq,
             const float* __restrict__ A_log, const float* __restrict__ dt_bias,
             float* __restrict__ dt_soft, float* __restrict__ Sbuf,
             float* __restrict__ Ebuf) {
    const int g = blockIdx.x, t = threadIdx.x;
    __shared__ float buf0[LSEQ], buf1[LSEQ];
    float dtr = zq[(size_t)t * NZ + D_SSM + g] + dt_bias[g];
    float dt = (dtr > 20.f) ? dtr : log1pf(expf(dtr));
    dt_soft[g * LSEQ + t] = dt;
    buf0[t] = dt;
    __syncthreads();
    float* src = buf0; float* dst = buf1;
    for (int off = 1; off < LSEQ; off <<= 1) {
        float v = src[t];
        if (t >= off) v += src[t - off];
        dst[t] = v;
        __syncthreads();
        float* tmp = src; src = dst; dst = tmp;
    }
    float A = -expf(A_log[g]);
    float S = A * src[t];
    Sbuf[g * LSEQ + t] = S;
    if ((t & (LC - 1)) == LC - 1) Ebuf[g * NC + (t >> 6)] = S;
}

// ---------------- S2: chunk states ----------------
__global__ __launch_bounds__(256)
void chunk_state(const float* __restrict__ xc, const float* __restrict__ dt_soft,
                 const float* __restrict__ Sbuf, const float* __restrict__ Ebuf,
                 float* __restrict__ Sc) {
    const int g = blockIdx.x, c = blockIdx.y;
    const int tid = threadIdx.x;
    const int t0 = c * LC;
    __shared__ __align__(16) float wB[LC][DS];
    __shared__ float Xs[LC][HD];
    __shared__ float sw[LC];

    if (tid < LC) {
        float Ec = Ebuf[g * NC + c];
        sw[tid] = expf(Ec - Sbuf[g * LSEQ + t0 + tid]) * dt_soft[g * LSEQ + t0 + tid];
    }
    __syncthreads();
    for (int i = tid; i < LC * DS; i += 256) {
        int r = i >> 6, s = i & 63;
        wB[r][s] = sw[r] * xc[(size_t)(t0 + r) * D_INNER + D_SSM + g * DS + s];
    }
    for (int i = tid; i < LC * HD; i += 256) {
        int r = i >> 7, h = i & 127;
        Xs[r][h] = xc[(size_t)(t0 + r) * D_INNER + g * HD + h];
    }
    __syncthreads();

    const int h = tid & 127, sh = (tid >> 7) * 32;
    float acc[32];
    #pragma unroll
    for (int j = 0; j < 32; j++) acc[j] = 0.f;
    for (int r = 0; r < LC; r++) {
        float xv = Xs[r][h];
        const float4* wrow = (const float4*)&wB[r][sh];
        #pragma unroll
        for (int q = 0; q < 8; q++) {
            float4 w4 = wrow[q];
            acc[4*q+0] += w4.x * xv;
            acc[4*q+1] += w4.y * xv;
            acc[4*q+2] += w4.z * xv;
            acc[4*q+3] += w4.w * xv;
        }
    }
    float* out = Sc + (size_t)(g * NC + c) * DS * HD;
    #pragma unroll
    for (int j = 0; j < 32; j++) out[(size_t)(sh + j) * HD + h] = acc[j];
}

// ---------------- S3: prefix over chunks ----------------
__global__ __launch_bounds__(256)
void chunk_prefix(const float* __restrict__ Sc, const float* __restrict__ Ebuf,
                  float* __restrict__ Hbuf) {
    const int g = blockIdx.y;
    const int e = blockIdx.x * 256 + threadIdx.x;
    float H = 0.f, Eprev = 0.f;
    for (int c = 0; c < NC; c++) {
        size_t base = (size_t)(g * NC + c) * DS * HD;
        Hbuf[base + e] = H;
        float Ec = Ebuf[g * NC + c];
        H = expf(Ec - Eprev) * H + Sc[base + e];
        Eprev = Ec;
    }
}

// ---------------- S4: per-chunk output + RMSNorm + SiLU(z), emits yg hi/lo ----
__global__ __launch_bounds__(256)
void chunk_output(const float* __restrict__ xc, const float* __restrict__ dt_soft,
                  const float* __restrict__ Sbuf, const float* __restrict__ Ebuf,
                  const float* __restrict__ Hbuf,
                  const float* __restrict__ zq, const float* __restrict__ norm_w,
                  ushort* __restrict__ ygH, ushort* __restrict__ ygL) {
    const int g = blockIdx.x, c = blockIdx.y;
    const int tid = threadIdx.x;
    const int t0 = c * LC;

    __shared__ __align__(16) float smem[4096 + 4096 + 8192];
    float* CT = smem;
    float* BW = smem + 4096;
    float* Xs = smem + 8192;
    float* red = smem;
    float* sscale = smem + 256;

    for (int i = tid; i < LC * DS; i += 256) {
        int t = i >> 6, s = i & 63;
        CT[s * LC + t] = xc[(size_t)(t0 + t) * D_INNER + D_SSM + NG * DS + g * DS + s];
        BW[t * DS + s] = xc[(size_t)(t0 + t) * D_INNER + D_SSM + g * DS + s];
    }
    for (int i = tid; i < LC * HD; i += 256) {
        int t = i >> 7, h = i & 127;
        Xs[t * HD + h] = xc[(size_t)(t0 + t) * D_INNER + g * HD + h];
    }
    __syncthreads();

    {
        const int t = tid & 63, tau0 = tid >> 6;
        float Greg[16];
        #pragma unroll
        for (int k = 0; k < 16; k++) Greg[k] = 0.f;
        for (int s = 0; s < DS; s++) {
            float cv = CT[s * LC + t];
            #pragma unroll
            for (int k = 0; k < 16; k++) Greg[k] += cv * BW[(tau0 + 4 * k) * DS + s];
        }
        __syncthreads();
        float St = Sbuf[g * LSEQ + t0 + t];
        #pragma unroll
        for (int k = 0; k < 16; k++) {
            int tau = tau0 + 4 * k;
            float w = 0.f;
            if (tau <= t)
                w = expf(St - Sbuf[g * LSEQ + t0 + tau]) *
                    dt_soft[g * LSEQ + t0 + tau] * Greg[k];
            BW[tau * LC + t] = w;
        }
    }
    __syncthreads();

    const int h = tid & 127, tb = (tid >> 7) * 32;
    float y[32], T[32];
    #pragma unroll
    for (int j = 0; j < 32; j++) { y[j] = 0.f; T[j] = 0.f; }

    for (int tau = 0; tau < LC; tau++) {
        float xv = Xs[tau * HD + h];
        const float4* wrow = (const float4*)&BW[tau * LC + tb];
        #pragma unroll
        for (int q = 0; q < 8; q++) {
            float4 w4 = wrow[q];
            y[4*q+0] += w4.x * xv;
            y[4*q+1] += w4.y * xv;
            y[4*q+2] += w4.z * xv;
            y[4*q+3] += w4.w * xv;
        }
    }
    {
        const float* Hg = Hbuf + (size_t)(g * NC + c) * DS * HD;
        for (int s = 0; s < DS; s++) {
            float Hv = Hg[(size_t)s * HD + h];
            const float* crow = &CT[s * LC + tb];
            #pragma unroll
            for (int j = 0; j < 32; j++) T[j] += crow[j] * Hv;
        }
    }
    float Eprev = (c > 0) ? Ebuf[g * NC + c - 1] : 0.f;
    #pragma unroll
    for (int j = 0; j < 32; j++) {
        int t = tb + j;
        float St = Sbuf[g * LSEQ + t0 + t];
        float Dv = zq[(size_t)(t0 + t) * NZ + D_SSM + NG + g];
        y[j] += expf(St - Eprev) * T[j] + Dv * Xs[t * HD + h];
    }
    __syncthreads();
    #pragma unroll
    for (int j = 0; j < 32; j++) Xs[(tb + j) * HD + h] = y[j];
    __syncthreads();

    {
        int t = tid >> 2, q = tid & 3;
        float p = 0.f;
        for (int i = 0; i < 32; i++) {
            float v = Xs[t * HD + q * 32 + i];
            p += v * v;
        }
        red[t * 4 + q] = p;
    }
    __syncthreads();
    if (tid < LC) {
        float s2 = red[tid*4] + red[tid*4+1] + red[tid*4+2] + red[tid*4+3];
        sscale[tid] = rsqrtf(s2 * (1.f / HD) + EPS_RMS);
    }
    __syncthreads();

    float nw = norm_w[h];
    #pragma unroll
    for (int j = 0; j < 32; j++) {
        int t = tb + j;
        float zv = zq[(size_t)(t0 + t) * NZ + g * HD + h];
        size_t idx = (size_t)(t0 + t) * D_SSM + g * HD + h;
        float val = y[j] * sscale[t] * nw * siluf(zv);
        unsigned short hb = f2bf(val);
        ygH[idx] = hb;
        ygL[idx] = f2bf(val - bf2f(hb));
    }
}

extern "C" void kernel_launch(void* const* d_in, const int* in_sizes, int n_in,
                              void* d_out, int out_size, void* d_ws, size_t ws_size,
                              hipStream_t stream) {
    const float* hs      = (const float*)d_in[0];
    const float* W_qkv   = (const float*)d_in[1];
    const float* W_z     = (const float*)d_in[2];
    const float* W_a     = (const float*)d_in[3];
    const float* W_b     = (const float*)d_in[4];
    const float* conv_w  = (const float*)d_in[5];
    const float* W_out   = (const float*)d_in[6];
    const float* norm_w  = (const float*)d_in[7];
    const float* A_log   = (const float*)d_in[8];
    const float* dt_bias = (const float*)d_in[9];
    float* out = (float*)d_out;

    float* ws      = (float*)d_ws;
    float* xBC     = ws;                                   // 8,388,608 f
    float* zq      = xBC + (size_t)LSEQ * D_INNER;         // 4,325,376 f
    float* dt_soft = zq + (size_t)LSEQ * NZ;               // 32768 f
    float* Sbuf    = dt_soft + (size_t)NG * LSEQ;          // 32768 f
    float* Ebuf    = Sbuf + (size_t)NG * LSEQ;             // 512 f
    ushort* hsH    = (ushort*)(Ebuf + 512);                // 2,621,440 us
    ushort* hsL    = hsH + (size_t)LSEQ * HID;
    ushort* WH     = hsL + (size_t)LSEQ * HID;             // NBIG*HID = 31,784,960 us
    ushort* WL     = WH + (size_t)NBIG * HID;
    // phase-2 overlay on WH/WL region (dead after gemm_big256):
    float* xconv   = (float*)WH;                           // 8,388,608 f
    float* Sc      = xconv + (size_t)LSEQ * D_INNER;       // 4,194,304 f
    float* Hbuf    = Sc + (size_t)NG * NC * DS * HD;       // 4,194,304 f
    ushort* ygH    = (ushort*)(Hbuf + (size_t)NG * NC * DS * HD);  // 4,194,304 us
    ushort* ygL    = ygH + (size_t)LSEQ * D_SSM;
    ushort* WoH    = ygL + (size_t)LSEQ * D_SSM;           // 10,485,760 us
    ushort* WoL    = WoH + (size_t)HID * D_SSM;

    dim3 blk(256);

    // input/weight planes
    split_cvt<<<dim3((LSEQ * HID / 4 + 255) / 256), blk, 0, stream>>>(
        (const float4*)hs, (ushort4*)hsH, (ushort4*)hsL, LSEQ * HID / 4);
    split_cvt<<<dim3(((D_INNER * HID) / 4 + 255) / 256), blk, 0, stream>>>(
        (const float4*)W_qkv, (ushort4*)WH, (ushort4*)WL, (D_INNER * HID) / 4);
    split_cvt<<<dim3(((D_SSM * HID) / 4 + 255) / 256), blk, 0, stream>>>(
        (const float4*)W_z,
        (ushort4*)(WH + (size_t)D_INNER * HID), (ushort4*)(WL + (size_t)D_INNER * HID),
        (D_SSM * HID) / 4);
    split_cvt<<<dim3(((NG * HID) / 4 + 255) / 256), blk, 0, stream>>>(
        (const float4*)W_b,
        (ushort4*)(WH + (size_t)(D_INNER + D_SSM) * HID),
        (ushort4*)(WL + (size_t)(D_INNER + D_SSM) * HID), (NG * HID) / 4);
    split_cvt<<<dim3(((NG * HID) / 4 + 255) / 256), blk, 0, stream>>>(
        (const float4*)W_a,
        (ushort4*)(WH + (size_t)(D_INNER + D_SSM + NG) * HID),
        (ushort4*)(WL + (size_t)(D_INNER + D_SSM + NG) * HID), (NG * HID) / 4);

    // merged projection GEMM: 256^2 tiles, deep-pipelined, K'=3K plane-concat
    gemm_big256<<<dim3(GB_BLOCKS), dim3(512), 0, stream>>>(
        hsH, hsL, WH, WL, xBC, zq);

    conv_silu<<<dim3((LSEQ * D_INNER) / 256), blk, 0, stream>>>(xBC, conv_w, xconv);

    dt_scan<<<dim3(NG), dim3(1024), 0, stream>>>(zq, A_log, dt_bias,
                                                 dt_soft, Sbuf, Ebuf);
    chunk_state<<<dim3(NG, NC), blk, 0, stream>>>(xconv, dt_soft, Sbuf, Ebuf, Sc);
    chunk_prefix<<<dim3(DS * HD / 256, NG), blk, 0, stream>>>(Sc, Ebuf, Hbuf);
    chunk_output<<<dim3(NG, NC), blk, 0, stream>>>(xconv, dt_soft, Sbuf, Ebuf,
                                                   Hbuf, zq, norm_w, ygH, ygL);

    // out = yg @ W_out^T, split-K x4 with atomic accumulate
    split_cvt<<<dim3(((HID * D_SSM) / 4 + 255) / 256), blk, 0, stream>>>(
        (const float4*)W_out, (ushort4*)WoH, (ushort4*)WoL, (HID * D_SSM) / 4);
    hipMemsetAsync(out, 0, (size_t)LSEQ * HID * sizeof(float), stream);
    gemm_out_splitk<<<dim3(HID / 128, LSEQ / 128, 4), blk, 0, stream>>>(
        ygH, ygL, WoH, WoL, out);
}